// Round 6
// baseline (309.674 us; speedup 1.0000x reference)
//
#include <hip/hip_runtime.h>
#include <hip/hip_bf16.h>

#define N_ROWS 16384   // B*T
#define K_CODES 4096
#define D_DIM 256

typedef short short8 __attribute__((ext_vector_type(8)));
typedef float floatx4 __attribute__((ext_vector_type(4)));

// async 16B global->LDS (dest = wave-uniform base + lane*16)
__device__ inline void gload_lds16(const void* g, void* l) {
    __builtin_amdgcn_global_load_lds(
        (const __attribute__((address_space(1))) void*)g,
        (__attribute__((address_space(3))) void*)l, 16, 0, 0);
}

// ------- pack x,e -> bf16 hi/lo global images (LDS-image order) + norms -------
// X: [rb][ch 8][part 2][r 128][ps 4] 16B units; content at (r,ps) holds dims
// d = ch*32 + (ps ^ (r&3))*8 .. +7. part0 = hi (trunc bf16), part1 = residual.
// One wave handles 2 rows: lane = sub(1)|q(5); q indexes 8-dim groups.
__global__ __launch_bounds__(256) void vq_pack(const float* __restrict__ x,
                                               const float* __restrict__ e,
                                               uint4* __restrict__ X,
                                               uint4* __restrict__ E,
                                               float* __restrict__ xx,
                                               float* __restrict__ en,
                                               double* __restrict__ loss_acc,
                                               unsigned int* __restrict__ ctr) {
    int tid  = threadIdx.x;
    int w    = blockIdx.x * 4 + (tid >> 6);   // 10240 waves
    int lane = tid & 63;
    int sub  = lane >> 5, q = lane & 31;
    const float* src;
    uint4* img;
    float* ndst;
    int row;
    if (w < 8192) { row = w * 2 + sub;          src = x; img = X; ndst = xx; }
    else          { row = (w - 8192) * 2 + sub; src = e; img = E; ndst = en; }
    int rb = row >> 7, r = row & 127;
    int ch = q >> 2, ps = (q & 3) ^ (r & 3);
    uint4* dstH = img + rb * 8192 + ch * 1024 + r * 4 + ps;        // part 0
    uint4* dstL = dstH + 512;                                       // part 1

    float4 v0 = *reinterpret_cast<const float4*>(&src[(size_t)row * D_DIM + q * 8]);
    float4 v1 = *reinterpret_cast<const float4*>(&src[(size_t)row * D_DIM + q * 8 + 4]);
    float f[8] = {v0.x, v0.y, v0.z, v0.w, v1.x, v1.y, v1.z, v1.w};

    float s = 0.f;
    unsigned int hh[8], ll[8];
#pragma unroll
    for (int i = 0; i < 8; ++i) {
        s += f[i] * f[i];
        unsigned int u = __float_as_uint(f[i]);
        hh[i] = u >> 16;                                            // trunc bf16
        float lo = f[i] - __uint_as_float(u & 0xFFFF0000u);         // exact residual
        ll[i] = __float_as_uint(lo) >> 16;
    }
#pragma unroll
    for (int m = 1; m <= 16; m <<= 1) s += __shfl_xor(s, m, 64);   // 32-lane reduce
    if (q == 0) ndst[row] = s;

    *dstH = make_uint4(hh[0] | (hh[1] << 16), hh[2] | (hh[3] << 16),
                       hh[4] | (hh[5] << 16), hh[6] | (hh[7] << 16));
    *dstL = make_uint4(ll[0] | (ll[1] << 16), ll[2] | (ll[3] << 16),
                       ll[4] | (ll[5] << 16), ll[6] | (ll[7] << 16));

    if (blockIdx.x == 0 && tid == 0) { *loss_acc = 0.0; *ctr = 0u; }
}

// ------- main: DMA-staged bf16 split MFMA GEMM + per-(row,cbk,wn) top-2 -------
__global__ __launch_bounds__(256) void vq_argmin(const uint4* __restrict__ X,
                                                 const uint4* __restrict__ E,
                                                 const float* __restrict__ en,
                                                 const float* __restrict__ xx,
                                                 unsigned long long* __restrict__ top2) {
    // LDS: 2048 units of 16B = 32 KB: xh[512] | xl[512] | eh[512] | el[512]
    __shared__ __align__(16) unsigned short sm[2048 * 8];

    int tid  = threadIdx.x;
    int cbk  = blockIdx.x & 31;
    int rb   = blockIdx.x >> 5;
    int r0   = rb * 128, c0 = cbk * 128;
    int lane = tid & 63;
    int wave = tid >> 6;
    int wm   = wave >> 1, wn = wave & 1;   // 2x2 wave grid, 64x64 per wave
    int l15  = lane & 15, lq = lane >> 4;

    floatx4 acc[4][4];
#pragma unroll
    for (int mt = 0; mt < 4; ++mt)
#pragma unroll
        for (int nt = 0; nt < 4; ++nt) acc[mt][nt] = (floatx4)0.f;

    const uint4* Ag = X + (size_t)rb  * 8192;   // 8 chunks * 1024 units
    const uint4* Bg = E + (size_t)cbk * 8192;

    const short8* Av = reinterpret_cast<const short8*>(sm);
    int sw = lq ^ (l15 & 3);
    int ua = (wm * 64 + l15) * 4 + sw;   // + mt*64 units per 16-row step
    int ub = (wn * 64 + l15) * 4 + sw;

    for (int ch = 0; ch < 8; ++ch) {     // 8 chunks of K=32 (hi+lo staged together)
        __syncthreads();
#pragma unroll
        for (int i = 0; i < 4; ++i) {
            int q = i * 256 + tid;       // 0..1023
            gload_lds16(Ag + ch * 1024 + q, (char*)sm + (i * 256 + wave * 64) * 16);
            gload_lds16(Bg + ch * 1024 + q, (char*)sm + ((1024 + i * 256) + wave * 64) * 16);
        }
        __syncthreads();

        short8 ah[4], al[4];
#pragma unroll
        for (int t = 0; t < 4; ++t) {
            ah[t] = Av[ua + t * 64];
            al[t] = Av[512 + ua + t * 64];
        }
#pragma unroll
        for (int nt = 0; nt < 4; ++nt) {
            short8 bh = Av[1024 + ub + nt * 64];
            short8 bl = Av[1536 + ub + nt * 64];
#pragma unroll
            for (int mt = 0; mt < 4; ++mt) {
                acc[mt][nt] = __builtin_amdgcn_mfma_f32_16x16x32_bf16(ah[mt], bh, acc[mt][nt], 0, 0, 0);
                acc[mt][nt] = __builtin_amdgcn_mfma_f32_16x16x32_bf16(ah[mt], bl, acc[mt][nt], 0, 0, 0);
                acc[mt][nt] = __builtin_amdgcn_mfma_f32_16x16x32_bf16(al[mt], bh, acc[mt][nt], 0, 0, 0);
            }
        }
    }

    // ---- epilogue stage 1: per-lane top-2 over nt -> LDS candidate table ----
    float xv[4][4], ev[4];
#pragma unroll
    for (int mt = 0; mt < 4; ++mt)
#pragma unroll
        for (int r = 0; r < 4; ++r)
            xv[mt][r] = xx[r0 + wm * 64 + mt * 16 + lq * 4 + r];
#pragma unroll
    for (int nt = 0; nt < 4; ++nt) ev[nt] = en[c0 + wn * 64 + nt * 16 + l15];

    __syncthreads();                       // all frag reads done; reuse sm
    unsigned long long* cand = (unsigned long long*)sm;   // [128 rows][2 wn][16 l15]

#pragma unroll
    for (int mt = 0; mt < 4; ++mt) {
#pragma unroll
        for (int r = 0; r < 4; ++r) {
            unsigned int b0 = 0xFFFFFFFFu, b1 = 0xFFFFFFFFu;
#pragma unroll
            for (int nt = 0; nt < 4; ++nt) {
                float dist = (xv[mt][r] + ev[nt]) - 2.0f * acc[mt][nt][r];
                unsigned int u = __float_as_uint(dist);
                u ^= (u & 0x80000000u) ? 0xFFFFFFFFu : 0x80000000u;   // order-preserving
                unsigned int key = (u & 0xFFFFF000u) |
                                   (unsigned)(c0 + wn * 64 + nt * 16 + l15);  // 12-bit idx
                if (key < b0) { b1 = b0; b0 = key; }
                else if (key < b1) b1 = key;
            }
            int row_local = wm * 64 + mt * 16 + lq * 4 + r;
            cand[(row_local * 2 + wn) * 16 + l15] =
                ((unsigned long long)b0 << 32) | b1;
        }
    }
    __syncthreads();

    // ---- stage 2: 256 threads, each merges 16 sorted pairs -> slot top-2 ----
    {
        unsigned int B0 = 0xFFFFFFFFu, B1 = 0xFFFFFFFFu;
        const unsigned long long* cb = cand + tid * 16;
#pragma unroll
        for (int j = 0; j < 8; ++j) {
            int o = ((j + tid) & 7) * 2;                   // rotated: bank-uniform
            unsigned long long p0 = cb[o], p1 = cb[o + 1];
            unsigned int o0 = (unsigned int)(p0 >> 32), o1 = (unsigned int)p0;
            unsigned int mx = B0 > o0 ? B0 : o0;
            B0 = B0 < o0 ? B0 : o0;
            unsigned int mn = B1 < o1 ? B1 : o1;
            B1 = mx < mn ? mx : mn;
            o0 = (unsigned int)(p1 >> 32); o1 = (unsigned int)p1;
            mx = B0 > o0 ? B0 : o0;
            B0 = B0 < o0 ? B0 : o0;
            mn = B1 < o1 ? B1 : o1;
            B1 = mx < mn ? mx : mn;
        }
        top2[(size_t)(r0 + (tid >> 1)) * 64 + cbk * 2 + (tid & 1)] =
            ((unsigned long long)B0 << 32) | B1;
    }
}

// ------- merge: global top-4, exact f64 rescore, output + loss + final -------
__global__ __launch_bounds__(256) void vq_merge(const float* __restrict__ x,
                                                const float* __restrict__ e,
                                                const float* __restrict__ en,
                                                const float* __restrict__ xx,
                                                const unsigned long long* __restrict__ top2,
                                                float* __restrict__ out,
                                                double* __restrict__ loss_acc,
                                                unsigned int* __restrict__ ctr) {
    int tid  = threadIdx.x;
    int lane = tid & 63;
    int wave = tid >> 6;
    int row  = blockIdx.x * 4 + wave;

    unsigned long long c = top2[(size_t)row * 64 + lane];
    unsigned int k0 = (unsigned int)(c >> 32);
    unsigned int k1 = (unsigned int)c;           // k0 <= k1 by construction
    unsigned int k2 = 0xFFFFFFFFu, k3 = 0xFFFFFFFFu;
#pragma unroll
    for (int m = 1; m <= 32; m <<= 1) {          // sorted-4 butterfly merge
        unsigned int o0 = __shfl_xor(k0, m, 64);
        unsigned int o1 = __shfl_xor(k1, m, 64);
        unsigned int o2 = __shfl_xor(k2, m, 64);
        unsigned int o3 = __shfl_xor(k3, m, 64);
        unsigned int t0 = min(k0, o0), s0 = max(k0, o0);
        unsigned int t1 = min(k1, o1), s1 = max(k1, o1);
        unsigned int t2 = min(k2, o2);
        unsigned int t3 = min(k3, o3);
        k0 = t0;
        k1 = min(s0, t1);
        unsigned int u = max(s0, t1);
        k2 = min(u, t2);
        k3 = min(max(u, t2), min(s1, t3));
    }
    int i0 = k0 & 0xFFF, i1 = k1 & 0xFFF, i2 = k2 & 0xFFF, i3 = k3 & 0xFFF;

    // exact rescore of 4 candidates in double
    float4 xv = reinterpret_cast<const float4*>(x)[(size_t)row * 64 + lane];
    float4 e0 = reinterpret_cast<const float4*>(e)[(size_t)i0 * 64 + lane];
    float4 e1 = reinterpret_cast<const float4*>(e)[(size_t)i1 * 64 + lane];
    float4 e2 = reinterpret_cast<const float4*>(e)[(size_t)i2 * 64 + lane];
    float4 e3 = reinterpret_cast<const float4*>(e)[(size_t)i3 * 64 + lane];
    double p0 = (double)xv.x * e0.x + (double)xv.y * e0.y + (double)xv.z * e0.z + (double)xv.w * e0.w;
    double p1 = (double)xv.x * e1.x + (double)xv.y * e1.y + (double)xv.z * e1.z + (double)xv.w * e1.w;
    double p2 = (double)xv.x * e2.x + (double)xv.y * e2.y + (double)xv.z * e2.z + (double)xv.w * e2.w;
    double p3 = (double)xv.x * e3.x + (double)xv.y * e3.y + (double)xv.z * e3.z + (double)xv.w * e3.w;
#pragma unroll
    for (int m = 32; m; m >>= 1) {
        p0 += __shfl_xor(p0, m, 64);
        p1 += __shfl_xor(p1, m, 64);
        p2 += __shfl_xor(p2, m, 64);
        p3 += __shfl_xor(p3, m, 64);
    }
    double xr = (double)xx[row];
    double d0 = (xr + (double)en[i0]) - 2.0 * p0;
    double d1 = (xr + (double)en[i1]) - 2.0 * p1;
    double d2 = (xr + (double)en[i2]) - 2.0 * p2;
    double d3 = (xr + (double)en[i3]) - 2.0 * p3;

    double bd = d0; int bi = i0; float4 v = e0;
    if (d1 < bd || (d1 == bd && i1 < bi)) { bd = d1; bi = i1; v = e1; }
    if (d2 < bd || (d2 == bd && i2 < bi)) { bd = d2; bi = i2; v = e2; }
    if (d3 < bd || (d3 == bd && i3 < bi)) { bd = d3; bi = i3; v = e3; }

    float4 o;
    o.x = xv.x + (v.x - xv.x);
    o.y = xv.y + (v.y - xv.y);
    o.z = xv.z + (v.z - xv.z);
    o.w = xv.w + (v.w - xv.w);
    reinterpret_cast<float4*>(out)[(size_t)row * 64 + lane] = o;
    if (lane == 0) out[(size_t)N_ROWS * D_DIM + row] = (float)bi;

    float sx = xv.x - v.x, sy = xv.y - v.y, sz = xv.z - v.z, sw = xv.w - v.w;
    float ls = sx * sx + sy * sy + sz * sz + sw * sw;
#pragma unroll
    for (int m = 32; m; m >>= 1) ls += __shfl_xor(ls, m, 64);
    __shared__ float lred[4];
    if (lane == 0) lred[wave] = ls;
    __syncthreads();
    if (tid == 0) {
        double tot = (double)lred[0] + (double)lred[1] + (double)lred[2] + (double)lred[3];
        atomicAdd(loss_acc, tot);
        __threadfence();                         // order my add before ctr bump
        unsigned int done = atomicAdd(ctr, 1u);
        if (done == gridDim.x - 1) {             // last block: write the scalar
            double L = atomicAdd(loss_acc, 0.0); // coherent device-scope read
            float Lf = (float)(L / (double)((size_t)N_ROWS * D_DIM));
            out[(size_t)N_ROWS * D_DIM + N_ROWS] = Lf + 0.2f * Lf;  // loss1 + BETA*loss2
        }
    }
}

extern "C" void kernel_launch(void* const* d_in, const int* in_sizes, int n_in,
                              void* d_out, int out_size, void* d_ws, size_t ws_size,
                              hipStream_t stream) {
    const float* x = (const float*)d_in[0];
    const float* e = (const float*)d_in[1];
    float* out = (float*)d_out;
    char* ws = (char*)d_ws;
    // ws: 0 loss(8B) | 16 ctr(4B) | 64 en 16KB | 16448 xx 64KB | 81984 top2 8MB
    //     | 8470592 Ximg 16MB | 25247808 Eimg 4MB  (~28.2 MB total)
    double* loss_acc = (double*)ws;
    unsigned int* ctr = (unsigned int*)(ws + 16);
    float* en = (float*)(ws + 64);
    float* xx = (float*)(ws + 64 + K_CODES * 4);
    unsigned long long* top2 = (unsigned long long*)(ws + 81984);
    uint4* Ximg = (uint4*)(ws + 8470592);
    uint4* Eimg = (uint4*)(ws + 25247808);

    vq_pack<<<2560, 256, 0, stream>>>(x, e, Ximg, Eimg, xx, en, loss_acc, ctr);
    vq_argmin<<<4096, 256, 0, stream>>>(Ximg, Eimg, en, xx, top2);
    vq_merge<<<4096, 256, 0, stream>>>(x, e, en, xx, top2, out, loss_acc, ctr);
}

// Round 7
// 182.389 us; speedup vs baseline: 1.6979x; 1.6979x over previous
//
#include <hip/hip_runtime.h>
#include <hip/hip_bf16.h>

#define N_ROWS 16384   // B*T
#define K_CODES 4096
#define D_DIM 256

typedef short short8 __attribute__((ext_vector_type(8)));
typedef float floatx4 __attribute__((ext_vector_type(4)));

// async 16B global->LDS (dest = wave-uniform base + lane*16)
__device__ inline void gload_lds16(const void* g, void* l) {
    __builtin_amdgcn_global_load_lds(
        (const __attribute__((address_space(1))) void*)g,
        (__attribute__((address_space(3))) void*)l, 16, 0, 0);
}

// ------- pack x,e -> bf16 hi/lo global images (LDS-image order) + norms -------
// X: [rb][ch 8][part 2][r 128][ps 4] 16B units; content at (r,ps) holds dims
// d = ch*32 + (ps ^ (r&3))*8 .. +7. part0 = hi (trunc bf16), part1 = residual.
// One wave handles 2 rows: lane = sub(1)|q(5); q indexes 8-dim groups.
__global__ __launch_bounds__(256) void vq_pack(const float* __restrict__ x,
                                               const float* __restrict__ e,
                                               uint4* __restrict__ X,
                                               uint4* __restrict__ E,
                                               float* __restrict__ xx,
                                               float* __restrict__ en) {
    int tid  = threadIdx.x;
    int w    = blockIdx.x * 4 + (tid >> 6);   // 10240 waves
    int lane = tid & 63;
    int sub  = lane >> 5, q = lane & 31;
    const float* src;
    uint4* img;
    float* ndst;
    int row;
    if (w < 8192) { row = w * 2 + sub;          src = x; img = X; ndst = xx; }
    else          { row = (w - 8192) * 2 + sub; src = e; img = E; ndst = en; }
    int rb = row >> 7, r = row & 127;
    int ch = q >> 2, ps = (q & 3) ^ (r & 3);
    uint4* dstH = img + rb * 8192 + ch * 1024 + r * 4 + ps;        // part 0
    uint4* dstL = dstH + 512;                                       // part 1

    float4 v0 = *reinterpret_cast<const float4*>(&src[(size_t)row * D_DIM + q * 8]);
    float4 v1 = *reinterpret_cast<const float4*>(&src[(size_t)row * D_DIM + q * 8 + 4]);
    float f[8] = {v0.x, v0.y, v0.z, v0.w, v1.x, v1.y, v1.z, v1.w};

    float s = 0.f;
    unsigned int hh[8], ll[8];
#pragma unroll
    for (int i = 0; i < 8; ++i) {
        s += f[i] * f[i];
        unsigned int u = __float_as_uint(f[i]);
        hh[i] = u >> 16;                                            // trunc bf16
        float lo = f[i] - __uint_as_float(u & 0xFFFF0000u);         // exact residual
        ll[i] = __float_as_uint(lo) >> 16;
    }
#pragma unroll
    for (int m = 1; m <= 16; m <<= 1) s += __shfl_xor(s, m, 64);   // 32-lane reduce
    if (q == 0) ndst[row] = s;

    *dstH = make_uint4(hh[0] | (hh[1] << 16), hh[2] | (hh[3] << 16),
                       hh[4] | (hh[5] << 16), hh[6] | (hh[7] << 16));
    *dstL = make_uint4(ll[0] | (ll[1] << 16), ll[2] | (ll[3] << 16),
                       ll[4] | (ll[5] << 16), ll[6] | (ll[7] << 16));
}

// ------- main: DMA-staged bf16 split MFMA GEMM + per-(row,cbk,wn) top-2 -------
__global__ __launch_bounds__(256) void vq_argmin(const uint4* __restrict__ X,
                                                 const uint4* __restrict__ E,
                                                 const float* __restrict__ en,
                                                 const float* __restrict__ xx,
                                                 unsigned long long* __restrict__ top2) {
    // LDS: 2048 units of 16B = 32 KB: xh[512] | xl[512] | eh[512] | el[512]
    __shared__ __align__(16) unsigned short sm[2048 * 8];

    int tid  = threadIdx.x;
    int cbk  = blockIdx.x & 31;
    int rb   = blockIdx.x >> 5;
    int r0   = rb * 128, c0 = cbk * 128;
    int lane = tid & 63;
    int wave = tid >> 6;
    int wm   = wave >> 1, wn = wave & 1;   // 2x2 wave grid, 64x64 per wave
    int l15  = lane & 15, lq = lane >> 4;

    floatx4 acc[4][4];
#pragma unroll
    for (int mt = 0; mt < 4; ++mt)
#pragma unroll
        for (int nt = 0; nt < 4; ++nt) acc[mt][nt] = (floatx4)0.f;

    const uint4* Ag = X + (size_t)rb  * 8192;   // 8 chunks * 1024 units
    const uint4* Bg = E + (size_t)cbk * 8192;

    const short8* Av = reinterpret_cast<const short8*>(sm);
    int sw = lq ^ (l15 & 3);
    int ua = (wm * 64 + l15) * 4 + sw;   // + mt*64 units per 16-row step
    int ub = (wn * 64 + l15) * 4 + sw;

    for (int ch = 0; ch < 8; ++ch) {     // 8 chunks of K=32 (hi+lo staged together)
        __syncthreads();
#pragma unroll
        for (int i = 0; i < 4; ++i) {
            int q = i * 256 + tid;       // 0..1023
            gload_lds16(Ag + ch * 1024 + q, (char*)sm + (i * 256 + wave * 64) * 16);
            gload_lds16(Bg + ch * 1024 + q, (char*)sm + ((1024 + i * 256) + wave * 64) * 16);
        }
        __syncthreads();

        short8 ah[4], al[4];
#pragma unroll
        for (int t = 0; t < 4; ++t) {
            ah[t] = Av[ua + t * 64];
            al[t] = Av[512 + ua + t * 64];
        }
#pragma unroll
        for (int nt = 0; nt < 4; ++nt) {
            short8 bh = Av[1024 + ub + nt * 64];
            short8 bl = Av[1536 + ub + nt * 64];
#pragma unroll
            for (int mt = 0; mt < 4; ++mt) {
                acc[mt][nt] = __builtin_amdgcn_mfma_f32_16x16x32_bf16(ah[mt], bh, acc[mt][nt], 0, 0, 0);
                acc[mt][nt] = __builtin_amdgcn_mfma_f32_16x16x32_bf16(ah[mt], bl, acc[mt][nt], 0, 0, 0);
                acc[mt][nt] = __builtin_amdgcn_mfma_f32_16x16x32_bf16(al[mt], bh, acc[mt][nt], 0, 0, 0);
            }
        }
    }

    // ---- epilogue stage 1: per-lane top-2 over nt -> LDS candidate table ----
    float xv[4][4], ev[4];
#pragma unroll
    for (int mt = 0; mt < 4; ++mt)
#pragma unroll
        for (int r = 0; r < 4; ++r)
            xv[mt][r] = xx[r0 + wm * 64 + mt * 16 + lq * 4 + r];
#pragma unroll
    for (int nt = 0; nt < 4; ++nt) ev[nt] = en[c0 + wn * 64 + nt * 16 + l15];

    __syncthreads();                       // all frag reads done; reuse sm
    unsigned long long* cand = (unsigned long long*)sm;   // [128 rows][2 wn][16 l15]

#pragma unroll
    for (int mt = 0; mt < 4; ++mt) {
#pragma unroll
        for (int r = 0; r < 4; ++r) {
            unsigned int b0 = 0xFFFFFFFFu, b1 = 0xFFFFFFFFu;
#pragma unroll
            for (int nt = 0; nt < 4; ++nt) {
                float dist = (xv[mt][r] + ev[nt]) - 2.0f * acc[mt][nt][r];
                unsigned int u = __float_as_uint(dist);
                u ^= (u & 0x80000000u) ? 0xFFFFFFFFu : 0x80000000u;   // order-preserving
                unsigned int key = (u & 0xFFFFF000u) |
                                   (unsigned)(c0 + wn * 64 + nt * 16 + l15);  // 12-bit idx
                if (key < b0) { b1 = b0; b0 = key; }
                else if (key < b1) b1 = key;
            }
            int row_local = wm * 64 + mt * 16 + lq * 4 + r;
            cand[(row_local * 2 + wn) * 16 + l15] =
                ((unsigned long long)b0 << 32) | b1;
        }
    }
    __syncthreads();

    // ---- stage 2: 256 threads, each merges 16 sorted pairs -> slot top-2 ----
    {
        unsigned int B0 = 0xFFFFFFFFu, B1 = 0xFFFFFFFFu;
        const unsigned long long* cb = cand + tid * 16;
#pragma unroll
        for (int j = 0; j < 8; ++j) {
            int o = ((j + tid) & 7) * 2;                   // rotated: bank-uniform
            unsigned long long p0 = cb[o], p1 = cb[o + 1];
            unsigned int o0 = (unsigned int)(p0 >> 32), o1 = (unsigned int)p0;
            unsigned int mx = B0 > o0 ? B0 : o0;
            B0 = B0 < o0 ? B0 : o0;
            unsigned int mn = B1 < o1 ? B1 : o1;
            B1 = mx < mn ? mx : mn;
            o0 = (unsigned int)(p1 >> 32); o1 = (unsigned int)p1;
            mx = B0 > o0 ? B0 : o0;
            B0 = B0 < o0 ? B0 : o0;
            mn = B1 < o1 ? B1 : o1;
            B1 = mx < mn ? mx : mn;
        }
        top2[(size_t)(r0 + (tid >> 1)) * 64 + cbk * 2 + (tid & 1)] =
            ((unsigned long long)B0 << 32) | B1;
    }
}

// ------- merge: global top-4, exact f64 rescore, output + partial loss -------
__global__ __launch_bounds__(256) void vq_merge(const float* __restrict__ x,
                                                const float* __restrict__ e,
                                                const float* __restrict__ en,
                                                const float* __restrict__ xx,
                                                const unsigned long long* __restrict__ top2,
                                                float* __restrict__ out,
                                                double* __restrict__ partials) {
    int tid  = threadIdx.x;
    int lane = tid & 63;
    int wave = tid >> 6;
    int row  = blockIdx.x * 4 + wave;

    unsigned long long c = top2[(size_t)row * 64 + lane];
    unsigned int k0 = (unsigned int)(c >> 32);
    unsigned int k1 = (unsigned int)c;           // k0 <= k1 by construction
    unsigned int k2 = 0xFFFFFFFFu, k3 = 0xFFFFFFFFu;
#pragma unroll
    for (int m = 1; m <= 32; m <<= 1) {          // sorted-4 butterfly merge
        unsigned int o0 = __shfl_xor(k0, m, 64);
        unsigned int o1 = __shfl_xor(k1, m, 64);
        unsigned int o2 = __shfl_xor(k2, m, 64);
        unsigned int o3 = __shfl_xor(k3, m, 64);
        unsigned int t0 = min(k0, o0), s0 = max(k0, o0);
        unsigned int t1 = min(k1, o1), s1 = max(k1, o1);
        unsigned int t2 = min(k2, o2);
        unsigned int t3 = min(k3, o3);
        k0 = t0;
        k1 = min(s0, t1);
        unsigned int u = max(s0, t1);
        k2 = min(u, t2);
        k3 = min(max(u, t2), min(s1, t3));
    }
    int i0 = k0 & 0xFFF, i1 = k1 & 0xFFF, i2 = k2 & 0xFFF, i3 = k3 & 0xFFF;

    // exact rescore of 4 candidates in double
    float4 xv = reinterpret_cast<const float4*>(x)[(size_t)row * 64 + lane];
    float4 e0 = reinterpret_cast<const float4*>(e)[(size_t)i0 * 64 + lane];
    float4 e1 = reinterpret_cast<const float4*>(e)[(size_t)i1 * 64 + lane];
    float4 e2 = reinterpret_cast<const float4*>(e)[(size_t)i2 * 64 + lane];
    float4 e3 = reinterpret_cast<const float4*>(e)[(size_t)i3 * 64 + lane];
    double p0 = (double)xv.x * e0.x + (double)xv.y * e0.y + (double)xv.z * e0.z + (double)xv.w * e0.w;
    double p1 = (double)xv.x * e1.x + (double)xv.y * e1.y + (double)xv.z * e1.z + (double)xv.w * e1.w;
    double p2 = (double)xv.x * e2.x + (double)xv.y * e2.y + (double)xv.z * e2.z + (double)xv.w * e2.w;
    double p3 = (double)xv.x * e3.x + (double)xv.y * e3.y + (double)xv.z * e3.z + (double)xv.w * e3.w;
#pragma unroll
    for (int m = 32; m; m >>= 1) {
        p0 += __shfl_xor(p0, m, 64);
        p1 += __shfl_xor(p1, m, 64);
        p2 += __shfl_xor(p2, m, 64);
        p3 += __shfl_xor(p3, m, 64);
    }
    double xr = (double)xx[row];
    double d0 = (xr + (double)en[i0]) - 2.0 * p0;
    double d1 = (xr + (double)en[i1]) - 2.0 * p1;
    double d2 = (xr + (double)en[i2]) - 2.0 * p2;
    double d3 = (xr + (double)en[i3]) - 2.0 * p3;

    double bd = d0; int bi = i0; float4 v = e0;
    if (d1 < bd || (d1 == bd && i1 < bi)) { bd = d1; bi = i1; v = e1; }
    if (d2 < bd || (d2 == bd && i2 < bi)) { bd = d2; bi = i2; v = e2; }
    if (d3 < bd || (d3 == bd && i3 < bi)) { bd = d3; bi = i3; v = e3; }

    float4 o;
    o.x = xv.x + (v.x - xv.x);
    o.y = xv.y + (v.y - xv.y);
    o.z = xv.z + (v.z - xv.z);
    o.w = xv.w + (v.w - xv.w);
    reinterpret_cast<float4*>(out)[(size_t)row * 64 + lane] = o;
    if (lane == 0) out[(size_t)N_ROWS * D_DIM + row] = (float)bi;

    float sx = xv.x - v.x, sy = xv.y - v.y, sz = xv.z - v.z, sw = xv.w - v.w;
    float ls = sx * sx + sy * sy + sz * sz + sw * sw;
#pragma unroll
    for (int m = 32; m; m >>= 1) ls += __shfl_xor(ls, m, 64);
    __shared__ float lred[4];
    if (lane == 0) lred[wave] = ls;
    __syncthreads();
    if (tid == 0)   // plain store — NO atomics (4096 same-address RMWs cost ~130us)
        partials[blockIdx.x] = (double)lred[0] + (double)lred[1]
                             + (double)lred[2] + (double)lred[3];
}

// ------- final: reduce 4096 partials, write loss scalar -------
__global__ __launch_bounds__(256) void vq_final(const double* __restrict__ partials,
                                                float* __restrict__ out) {
    int tid = threadIdx.x;
    double s = 0.0;
#pragma unroll
    for (int i = 0; i < 16; ++i) s += partials[tid + i * 256];
#pragma unroll
    for (int m = 32; m; m >>= 1) s += __shfl_xor(s, m, 64);
    __shared__ double dred[4];
    if ((tid & 63) == 0) dred[tid >> 6] = s;
    __syncthreads();
    if (tid == 0) {
        double tot = dred[0] + dred[1] + dred[2] + dred[3];
        float L = (float)(tot / (double)((size_t)N_ROWS * D_DIM));
        out[(size_t)N_ROWS * D_DIM + N_ROWS] = L + 0.2f * L;   // loss1 + BETA*loss2
    }
}

extern "C" void kernel_launch(void* const* d_in, const int* in_sizes, int n_in,
                              void* d_out, int out_size, void* d_ws, size_t ws_size,
                              hipStream_t stream) {
    const float* x = (const float*)d_in[0];
    const float* e = (const float*)d_in[1];
    float* out = (float*)d_out;
    char* ws = (char*)d_ws;
    // ws: 0 partials[4096] f64 32KB | 32768 en 16KB | 49152 xx 64KB
    //     | 114688 top2 8MB | 8503296 Ximg 16MB | 25280512 Eimg 4MB (~29.5MB)
    double* partials = (double*)ws;
    float* en = (float*)(ws + 32768);
    float* xx = (float*)(ws + 49152);
    unsigned long long* top2 = (unsigned long long*)(ws + 114688);
    uint4* Ximg = (uint4*)(ws + 8503296);
    uint4* Eimg = (uint4*)(ws + 25280512);

    vq_pack<<<2560, 256, 0, stream>>>(x, e, Ximg, Eimg, xx, en);
    vq_argmin<<<4096, 256, 0, stream>>>(Ximg, Eimg, en, xx, top2);
    vq_merge<<<4096, 256, 0, stream>>>(x, e, en, xx, top2, out, partials);
    vq_final<<<1, 256, 0, stream>>>(partials, out);
}